// Round 1
// baseline (167.652 us; speedup 1.0000x reference)
//
#include <hip/hip_runtime.h>
#include <math.h>

#define N_INST 64
#define HW 64000   // 200*320 pixels
#define PIX_BLOCKS 250  // 250*256 == 64000 exactly

__device__ __forceinline__ float sigmoidf_(float x) {
    return 1.0f / (1.0f + __expf(-x));
}

// K1: logit[i*64+j] for all 4096 (i,j) pairs.
// grid 16 x 256; wave = one i (lanes j=0..63) -> cls_idx[i] wave-uniform.
__global__ void k_logit(const float* __restrict__ bbox,
                        const int* __restrict__ cls_idx,
                        const float* __restrict__ U_w,
                        const float* __restrict__ V_w,
                        const float* __restrict__ Wc_w,
                        const float* __restrict__ P_w,
                        float* __restrict__ logit) {
    int idx = blockIdx.x * blockDim.x + threadIdx.x;   // 0..4095
    int i = idx >> 6;
    int j = idx & 63;
    int ci = cls_idx[i] - 1;   // 0..79
    int cj = cls_idx[j] - 1;

    // class relation term: sum_c relu(U[c][ci]) * relu(V[c][cj]) * P[c]
    float acc = 0.0f;
#pragma unroll 8
    for (int c = 0; c < 256; ++c) {
        float a = U_w[c * 80 + ci];
        float b = V_w[c * 80 + cj];
        a = fmaxf(a, 0.0f);
        b = fmaxf(b, 0.0f);
        acc = fmaf(a * b, P_w[c], acc);
    }

    // bbox geometry term
    float xmin_i = bbox[i * 5 + 1], ymin_i = bbox[i * 5 + 2];
    float xmax_i = bbox[i * 5 + 3], ymax_i = bbox[i * 5 + 4];
    float xmin_j = bbox[j * 5 + 1], ymin_j = bbox[j * 5 + 2];
    float xmax_j = bbox[j * 5 + 3], ymax_j = bbox[j * 5 + 4];
    float wi = xmax_i - xmin_i + 1.0f, hi = ymax_i - ymin_i + 1.0f;
    float wj = xmax_j - xmin_j + 1.0f, hj = ymax_j - ymin_j + 1.0f;
    float xci = xmin_i + 0.5f * wi, yci = ymin_i + 0.5f * hi;
    float xcj = xmin_j + 0.5f * wj, ycj = ymin_j + 0.5f * hj;
    float dx = -(xci - xcj) / wi;
    float dy = -(yci - ycj) / hi;
    float dw = __logf(wj / wi);
    float dh = __logf(hj / hi);

#pragma unroll 8
    for (int o = 0; o < 128; ++o) {
        float s = dx * Wc_w[o * 4 + 0] + dy * Wc_w[o * 4 + 1]
                + dw * Wc_w[o * 4 + 2] + dh * Wc_w[o * 4 + 3];
        s = fmaxf(s, 0.0f);
        acc = fmaf(s, P_w[256 + o], acc);
    }

    logit[idx] = acc;
}

// K1b: O[i][j] = relu(sigmoid(logit[i][j]) - sigmoid(logit[j][i]))
__global__ void k_relu_R(const float* __restrict__ logit,
                         float* __restrict__ O_out) {
    int idx = blockIdx.x * blockDim.x + threadIdx.x;   // 0..4095
    int i = idx >> 6;
    int j = idx & 63;
    float r = sigmoidf_(logit[i * 64 + j]) - sigmoidf_(logit[j * 64 + i]);
    O_out[idx] = fmaxf(r, 0.0f);
}

// K2: the heavy fused kernel. One lane per pixel p.
//   t[j] = sigmoid(mask[j][p]);  w_i = sum_j O[i][j] t[j]
//   out[i][p] = m[i] * (1 - t[i] * w_i)
// m[], t[] fully in VGPRs (loops fully unrolled -> static indices, no scratch).
// O row addresses are wave-uniform + constant offset -> expect s_load promotion.
__global__ __launch_bounds__(256, 1) void k_mask(const float* __restrict__ mask,
                                                 const float* __restrict__ O,
                                                 float* __restrict__ out) {
    const int p = blockIdx.x * 256 + threadIdx.x;   // exact: 250*256 == 64000

    float m[N_INST];
    float t[N_INST];
#pragma unroll
    for (int j = 0; j < N_INST; ++j) {
        m[j] = mask[j * HW + p];
    }
#pragma unroll
    for (int j = 0; j < N_INST; ++j) {
        t[j] = sigmoidf_(m[j]);
    }

    const float4* __restrict__ O4 = (const float4*)O;
#pragma unroll
    for (int i = 0; i < N_INST; ++i) {
        float w = 0.0f;
#pragma unroll
        for (int q = 0; q < 16; ++q) {
            float4 o = O4[i * 16 + q];
            w = fmaf(o.x, t[4 * q + 0], w);
            w = fmaf(o.y, t[4 * q + 1], w);
            w = fmaf(o.z, t[4 * q + 2], w);
            w = fmaf(o.w, t[4 * q + 3], w);
        }
        out[i * HW + p] = m[i] * (1.0f - t[i] * w);
    }
}

extern "C" void kernel_launch(void* const* d_in, const int* in_sizes, int n_in,
                              void* d_out, int out_size, void* d_ws, size_t ws_size,
                              hipStream_t stream) {
    const float* mask   = (const float*)d_in[0];   // (1,64,200,320)
    const float* bbox   = (const float*)d_in[1];   // (64,5)
    const int*   cls    = (const int*)d_in[2];     // (64,)
    const float* U_w    = (const float*)d_in[3];   // (256,80)
    const float* V_w    = (const float*)d_in[4];   // (256,80)
    const float* Wc_w   = (const float*)d_in[5];   // (128,4)
    const float* P_w    = (const float*)d_in[6];   // (1,384)

    float* out_mask = (float*)d_out;                         // 4,096,000 floats
    float* out_O    = (float*)d_out + (size_t)N_INST * HW;   // 4096 floats
    float* logit_ws = (float*)d_ws;                          // 4096 floats scratch

    // K1: 4096 pair logits
    k_logit<<<16, 256, 0, stream>>>(bbox, cls, U_w, V_w, Wc_w, P_w, logit_ws);
    // K1b: O = relu(R - R^T), written straight into the O output slot
    k_relu_R<<<16, 256, 0, stream>>>(logit_ws, out_O);
    // K2: fused sigmoid + 64x64 matvec per pixel + mask update
    k_mask<<<PIX_BLOCKS, 256, 0, stream>>>(mask, out_O, out_mask);
}

// Round 2
// 101.321 us; speedup vs baseline: 1.6547x; 1.6547x over previous
//
#include <hip/hip_runtime.h>
#include <math.h>

#define N_INST 64
#define HW 64000        // 200*320 pixels
#define TP 64           // pixels per k_mask block
#define MASK_BLOCKS (HW / TP)   // 1000

__device__ __forceinline__ float sigmoidf_(float x) {
    return 1.0f / (1.0f + __expf(-x));
}

// -------- workspace layout (floats) --------
// [0,     4096)   logit[i][j]
// [4096,  8192)   OT[j][i]  (O transposed)
// [8192,  24576)  Afp[i][c] = relu(U[c][cls_i-1]) * P[c]   (64 x 256)
// [24576, 40960)  BfT[c][j] = relu(V[c][cls_j-1])          (256 x 64)

// K0: gather per-instance class columns into dense, matmul-friendly layouts.
// grid 64 x 256. Block b: Afp row b (lanes = c) and BfT rows 4b..4b+3.
__global__ void k_gather(const int* __restrict__ cls,
                         const float* __restrict__ U_w,
                         const float* __restrict__ V_w,
                         const float* __restrict__ P_w,
                         float* __restrict__ Afp,
                         float* __restrict__ BfT) {
    const int b = blockIdx.x;     // 0..63
    const int tid = threadIdx.x;  // 0..255
    // Afp[b][tid]: cls[b] is wave-uniform; gather stride-320B, write coalesced.
    const int cb = cls[b] - 1;
    float u = U_w[tid * 80 + cb];
    Afp[b * 256 + tid] = fmaxf(u, 0.0f) * P_w[tid];
    // BfT[c][j] for c = 4b + tid/64: per-lane gather on cls[j], write coalesced.
    const int c = b * 4 + (tid >> 6);
    const int j = tid & 63;
    const int cj = cls[j] - 1;
    float v = V_w[c * 80 + cj];
    BfT[c * 64 + j] = fmaxf(v, 0.0f);
}

// K1: logit[i][j]. Block = one i (so Afp row is provably wave-uniform -> s_load),
// lane = j. Class loop: 1 s_load + 1 coalesced vload + 1 fma per c.
__global__ __launch_bounds__(64) void k_pair(const float* __restrict__ bbox,
                                             const float* __restrict__ Afp,
                                             const float* __restrict__ BfT,
                                             const float* __restrict__ Wc_w,
                                             const float* __restrict__ P_w,
                                             float* __restrict__ logit) {
    const int i = blockIdx.x;
    const int j = threadIdx.x;

    const float* __restrict__ ai = Afp + i * 256;   // uniform base
    float acc = 0.0f;
#pragma unroll 16
    for (int c = 0; c < 256; ++c) {
        acc = fmaf(ai[c], BfT[c * 64 + j], acc);
    }

    // bbox geometry term (i-side values wave-uniform)
    float xmin_i = bbox[i * 5 + 1], ymin_i = bbox[i * 5 + 2];
    float xmax_i = bbox[i * 5 + 3], ymax_i = bbox[i * 5 + 4];
    float xmin_j = bbox[j * 5 + 1], ymin_j = bbox[j * 5 + 2];
    float xmax_j = bbox[j * 5 + 3], ymax_j = bbox[j * 5 + 4];
    float wi = xmax_i - xmin_i + 1.0f, hi = ymax_i - ymin_i + 1.0f;
    float wj = xmax_j - xmin_j + 1.0f, hj = ymax_j - ymin_j + 1.0f;
    float xci = xmin_i + 0.5f * wi, yci = ymin_i + 0.5f * hi;
    float xcj = xmin_j + 0.5f * wj, ycj = ymin_j + 0.5f * hj;
    float dx = -(xci - xcj) / wi;
    float dy = -(yci - ycj) / hi;
    float dw = __logf(wj / wi);
    float dh = __logf(hj / hi);

#pragma unroll 8
    for (int o = 0; o < 128; ++o) {
        float s = dx * Wc_w[o * 4 + 0] + dy * Wc_w[o * 4 + 1]
                + dw * Wc_w[o * 4 + 2] + dh * Wc_w[o * 4 + 3];
        s = fmaxf(s, 0.0f);
        acc = fmaf(s, P_w[256 + o], acc);
    }

    logit[i * 64 + j] = acc;
}

// K2: O = relu(sigmoid(L) - sigmoid(L^T)); write O (output) and OT (workspace,
// transposed so k_mask's LDS staging is coalesced).
__global__ void k_relu_R(const float* __restrict__ logit,
                         float* __restrict__ O_out,
                         float* __restrict__ OT_ws) {
    const int idx = blockIdx.x * blockDim.x + threadIdx.x;   // 0..4095
    const int i = idx >> 6;
    const int j = idx & 63;
    float r = sigmoidf_(logit[i * 64 + j]) - sigmoidf_(logit[j * 64 + i]);
    r = fmaxf(r, 0.0f);
    O_out[i * 64 + j] = r;       // coalesced
    OT_ws[j * 64 + i] = r;       // scattered, but only 4096 elements total
}

// K3: fused mask update. Block = 64-pixel tile x all 64 instances.
// Phase 1: t = sigmoid(mask tile) into LDS (computed ONCE per pixel).
// Phase 2: each thread owns 4i x 4p micro-tile; per j: 2x ds_read_b128 + 16 FMA.
// Grid = 1000 blocks -> ~15.6 waves/CU (vs 3.9 in R1).
__global__ __launch_bounds__(256) void k_mask(const float* __restrict__ mask,
                                              const float* __restrict__ OT,
                                              float* __restrict__ out) {
    __shared__ float t_lds[64][64];   // t[j][p_local]
    __shared__ float o_lds[64][64];   // O^T[j][i]
    const int tid = threadIdx.x;
    const int pbase = blockIdx.x * TP;

    // stage O^T (coalesced: 16 floats/thread)
#pragma unroll
    for (int k = 0; k < 16; ++k) {
        int idx = k * 256 + tid;
        ((float*)o_lds)[idx] = OT[idx];
    }
    // phase 1: sigmoid into LDS (coalesced mask reads)
    {
        const int j0 = tid >> 6;   // 0..3
        const int p  = tid & 63;
#pragma unroll
        for (int k = 0; k < 16; ++k) {
            int j = j0 * 16 + k;
            float m = mask[j * HW + pbase + p];
            t_lds[j][p] = sigmoidf_(m);
        }
    }
    __syncthreads();

    // phase 2
    const int pg = tid & 15;   // pixels pg*4 .. pg*4+3
    const int ig = tid >> 4;   // i = ig*4 .. ig*4+3
    float acc[4][4];
#pragma unroll
    for (int a = 0; a < 4; ++a)
#pragma unroll
        for (int b = 0; b < 4; ++b) acc[a][b] = 0.0f;

#pragma unroll 8
    for (int j = 0; j < 64; ++j) {
        float4 t4 = *(const float4*)&t_lds[j][pg * 4];
        float4 o4 = *(const float4*)&o_lds[j][ig * 4];
        acc[0][0] = fmaf(o4.x, t4.x, acc[0][0]);
        acc[0][1] = fmaf(o4.x, t4.y, acc[0][1]);
        acc[0][2] = fmaf(o4.x, t4.z, acc[0][2]);
        acc[0][3] = fmaf(o4.x, t4.w, acc[0][3]);
        acc[1][0] = fmaf(o4.y, t4.x, acc[1][0]);
        acc[1][1] = fmaf(o4.y, t4.y, acc[1][1]);
        acc[1][2] = fmaf(o4.y, t4.z, acc[1][2]);
        acc[1][3] = fmaf(o4.y, t4.w, acc[1][3]);
        acc[2][0] = fmaf(o4.z, t4.x, acc[2][0]);
        acc[2][1] = fmaf(o4.z, t4.y, acc[2][1]);
        acc[2][2] = fmaf(o4.z, t4.z, acc[2][2]);
        acc[2][3] = fmaf(o4.z, t4.w, acc[2][3]);
        acc[3][0] = fmaf(o4.w, t4.x, acc[3][0]);
        acc[3][1] = fmaf(o4.w, t4.y, acc[3][1]);
        acc[3][2] = fmaf(o4.w, t4.z, acc[3][2]);
        acc[3][3] = fmaf(o4.w, t4.w, acc[3][3]);
    }

    // epilogue: out[i][p] = m[i][p] * (1 - t[i][p] * w[i][p])
#pragma unroll
    for (int a = 0; a < 4; ++a) {
        const int i = ig * 4 + a;
        float4 ti = *(const float4*)&t_lds[i][pg * 4];
        float4 mi = *(const float4*)(mask + (size_t)i * HW + pbase + pg * 4);  // L1-hot
        float4 r;
        r.x = mi.x * (1.0f - ti.x * acc[a][0]);
        r.y = mi.y * (1.0f - ti.y * acc[a][1]);
        r.z = mi.z * (1.0f - ti.z * acc[a][2]);
        r.w = mi.w * (1.0f - ti.w * acc[a][3]);
        *(float4*)(out + (size_t)i * HW + pbase + pg * 4) = r;
    }
}

extern "C" void kernel_launch(void* const* d_in, const int* in_sizes, int n_in,
                              void* d_out, int out_size, void* d_ws, size_t ws_size,
                              hipStream_t stream) {
    const float* mask = (const float*)d_in[0];
    const float* bbox = (const float*)d_in[1];
    const int*   cls  = (const int*)d_in[2];
    const float* U_w  = (const float*)d_in[3];
    const float* V_w  = (const float*)d_in[4];
    const float* Wc_w = (const float*)d_in[5];
    const float* P_w  = (const float*)d_in[6];

    float* out_mask = (float*)d_out;                         // 4,096,000 floats
    float* out_O    = (float*)d_out + (size_t)N_INST * HW;   // 4096 floats

    float* ws    = (float*)d_ws;
    float* logit = ws;           // 4096
    float* OT    = ws + 4096;    // 4096
    float* Afp   = ws + 8192;    // 16384
    float* BfT   = ws + 24576;   // 16384

    k_gather<<<64, 256, 0, stream>>>(cls, U_w, V_w, P_w, Afp, BfT);
    k_pair<<<64, 64, 0, stream>>>(bbox, Afp, BfT, Wc_w, P_w, logit);
    k_relu_R<<<16, 256, 0, stream>>>(logit, out_O, OT);
    k_mask<<<MASK_BLOCKS, 256, 0, stream>>>(mask, OT, out_mask);
}